// Round 3
// baseline (319.926 us; speedup 1.0000x reference)
//
#include <hip/hip_runtime.h>
#include <hip/hip_bf16.h>
#include <stdint.h>

#define T_TOK 4096
#define NEXP  8
#define HDIM  1024
#define IDIM  2048
#define TOPK  2

typedef __attribute__((ext_vector_type(8))) short short8;
typedef __attribute__((ext_vector_type(4))) float f32x4;

__device__ __forceinline__ unsigned short f2bf(float f) {
    union { float f; unsigned int u; } v; v.f = f;
    unsigned int u = v.u;
    return (unsigned short)((u + 0x7fffu + ((u >> 16) & 1u)) >> 16);
}
__device__ __forceinline__ float bf2f(unsigned short s) {
    union { unsigned int u; float f; } v; v.u = ((unsigned int)s) << 16;
    return v.f;
}
__device__ __forceinline__ void gload_lds16(const void* g, void* l) {
    __builtin_amdgcn_global_load_lds(
        (const __attribute__((address_space(1))) unsigned int*)g,
        (__attribute__((address_space(3))) unsigned int*)l,
        16, 0, 0);
}

// ---------------- routing ----------------

__global__ void init_k(int* cnt) {
    if (threadIdx.x < NEXP) cnt[threadIdx.x] = 0;
}

__global__ void router_k(const float* __restrict__ logits, int* __restrict__ cnt,
                         int* __restrict__ eids, float* __restrict__ ews) {
    int t = blockIdx.x * blockDim.x + threadIdx.x;
    if (t >= T_TOK) return;
    const float4* lp = (const float4*)(logits + (size_t)t * NEXP);
    float4 a = lp[0], b = lp[1];
    float l[NEXP] = {a.x, a.y, a.z, a.w, b.x, b.y, b.z, b.w};
    int e0 = 0; float b0 = l[0];
    #pragma unroll
    for (int e = 1; e < NEXP; ++e) if (l[e] > b0) { b0 = l[e]; e0 = e; }
    int e1 = -1; float b1 = -1e30f;
    #pragma unroll
    for (int e = 0; e < NEXP; ++e) { if (e == e0) continue; if (l[e] > b1) { b1 = l[e]; e1 = e; } }
    float tt = __expf(b1 - b0);
    float w0 = 1.0f / (1.0f + tt);
    float w1 = 1.0f - w0;
    eids[2 * t] = e0; eids[2 * t + 1] = e1;
    ews[2 * t] = w0;  ews[2 * t + 1] = w1;
    atomicAdd(&cnt[e0], 1); atomicAdd(&cnt[e1], 1);
}

__global__ void offs_k(const int* __restrict__ cnt, int* __restrict__ offs, int* __restrict__ cursor) {
    if (threadIdx.x == 0) {
        int s = 0;
        for (int e = 0; e < NEXP; ++e) { offs[e] = s; cursor[e] = s; s += cnt[e]; }
        offs[NEXP] = s;
    }
}

__global__ void scatter_k(const int* __restrict__ eids, const float* __restrict__ ews,
                          int* __restrict__ cursor, int* __restrict__ tokid,
                          float* __restrict__ tokw, int* __restrict__ pos) {
    int t = blockIdx.x * blockDim.x + threadIdx.x;
    if (t >= T_TOK) return;
    #pragma unroll
    for (int k = 0; k < TOPK; ++k) {
        int e = eids[2 * t + k];
        int p = atomicAdd(&cursor[e], 1);
        tokid[p] = t; tokw[p] = ews[2 * t + k]; pos[2 * t + k] = p;
    }
}

// ---------------- fp32 -> bf16 convert ----------------

__global__ void cvt_all_k(const float* __restrict__ x, const float* __restrict__ w13,
                          const float* __restrict__ w2, unsigned short* __restrict__ xb,
                          unsigned short* __restrict__ w13b, unsigned short* __restrict__ w2b) {
    const int n0 = T_TOK * HDIM / 8;
    const int n1 = NEXP * 2 * IDIM * HDIM / 8;
    const int n2 = NEXP * HDIM * IDIM / 8;
    const int total = n0 + n1 + n2;
    for (int i = blockIdx.x * blockDim.x + threadIdx.x; i < total; i += gridDim.x * blockDim.x) {
        const float* s; unsigned short* d; int j;
        if (i < n0) { s = x; d = xb; j = i; }
        else if (i < n0 + n1) { s = w13; d = w13b; j = i - n0; }
        else { s = w2; d = w2b; j = i - n0 - n1; }
        const float4* p = (const float4*)(s + (size_t)j * 8);
        float4 a = p[0], b = p[1];
        union { unsigned short us[8]; short8 v; } r;
        r.us[0] = f2bf(a.x); r.us[1] = f2bf(a.y); r.us[2] = f2bf(a.z); r.us[3] = f2bf(a.w);
        r.us[4] = f2bf(b.x); r.us[5] = f2bf(b.y); r.us[6] = f2bf(b.z); r.us[7] = f2bf(b.w);
        *(short8*)(d + (size_t)j * 8) = r.v;
    }
}

// ---------------- GEMM1: h = silu(x@W1^T) * (x@W3^T) ----------------
// 256 tokens x 128 out-cols (B-tile = per-wave interleaved 32 gate + 32 up rows)
// BK=32, 4 circular LDS buffers (4x32KB), stage kt+2 while computing kt,
// counted vmcnt(4) (never 0). 512 thr / 8 waves (2M x 4N).
// grid (IDIM/128=16, 16, NEXP)

__global__ __launch_bounds__(512, 1) void gemm1_k(
    const unsigned short* __restrict__ xb, const unsigned short* __restrict__ w13b,
    const int* __restrict__ tokid, const int* __restrict__ offs,
    unsigned short* __restrict__ hbuf)
{
    extern __shared__ unsigned short lds[];   // 4 x 16384 ushorts
    const int e = blockIdx.z;
    const int off_e = offs[e];
    const int cnt_e = offs[e + 1] - off_e;
    const int mt = blockIdx.y;
    if (mt * 256 >= cnt_e) return;
    const int nt = blockIdx.x;

    const int tid = threadIdx.x;
    const int w = tid >> 6, lane = tid & 63;
    const int ln15 = lane & 15, l16 = lane >> 4;
    const int wm = w >> 2, wn = w & 3;

    // staging: per k-tile, A = 256 rows x 32 cols (2 chunks/thr), B same (2 chunks/thr)
    const char* srcA[2]; const char* srcB[2];
    int dstA[2], dstB[2];
    #pragma unroll
    for (int j = 0; j < 2; ++j) {
        int S = j * 512 + tid;
        int row = S >> 2, sRaw = S & 3;
        int ko = (sRaw ^ (row & 3)) * 8;       // element offset within k-tile (inverse swizzle)
        int tr = mt * 256 + row; if (tr >= cnt_e) tr = cnt_e - 1;
        srcA[j] = (const char*)(xb + (size_t)tokid[off_e + tr] * HDIM + ko);
        dstA[j] = S * 8;
        int grp = row >> 6, sub = row & 63;
        int gr = (sub < 32) ? (nt * 128 + grp * 32 + sub)
                            : (IDIM + nt * 128 + grp * 32 + (sub - 32));
        srcB[j] = (const char*)(w13b + (size_t)e * (2 * IDIM * HDIM) + (size_t)gr * HDIM + ko);
        dstB[j] = 8192 + S * 8;
    }

    const f32x4 z4 = {0.f, 0.f, 0.f, 0.f};
    f32x4 acc[8][4];
    #pragma unroll
    for (int m = 0; m < 8; ++m)
        #pragma unroll
        for (int n = 0; n < 4; ++n) acc[m][n] = z4;

    // read offsets (ushort units): slot xor is uniform in m,n since 16|row-step
    const int sl = (l16 ^ (ln15 & 3)) * 8;
    const int abase = (wm * 128 + ln15) * 32 + sl;
    const int bbase = 8192 + (wn * 64 + ln15) * 32 + sl;

    // prologue: stage tiles 0 and 1
    #pragma unroll
    for (int t = 0; t < 2; ++t) {
        unsigned short* sb = lds + t * 16384;
        gload_lds16(srcA[0] + t * 64, sb + dstA[0]);
        gload_lds16(srcA[1] + t * 64, sb + dstA[1]);
        gload_lds16(srcB[0] + t * 64, sb + dstB[0]);
        gload_lds16(srcB[1] + t * 64, sb + dstB[1]);
    }
    asm volatile("s_waitcnt vmcnt(4)" ::: "memory");
    __builtin_amdgcn_s_barrier();

    #pragma unroll 4
    for (int kt = 0; kt < 32; ++kt) {
        const unsigned short* buf = lds + (kt & 3) * 16384;
        unsigned short* sb = lds + ((kt + 2) & 3) * 16384;
        const size_t koff = (size_t)((kt + 2 < 32) ? kt + 2 : 31) * 64;

        short8 a[4], b[4];
        // ---- phase 0: m0-3, stage A(kt+2)
        #pragma unroll
        for (int m = 0; m < 4; ++m) a[m] = *(const short8*)&buf[abase + m * 512];
        #pragma unroll
        for (int n = 0; n < 4; ++n) b[n] = *(const short8*)&buf[bbase + n * 512];
        gload_lds16(srcA[0] + koff, sb + dstA[0]);
        gload_lds16(srcA[1] + koff, sb + dstA[1]);
        __builtin_amdgcn_sched_barrier(0);
        __builtin_amdgcn_s_barrier();
        __builtin_amdgcn_s_setprio(1);
        #pragma unroll
        for (int m = 0; m < 4; ++m)
            #pragma unroll
            for (int n = 0; n < 4; ++n)
                acc[m][n] = __builtin_amdgcn_mfma_f32_16x16x32_bf16(a[m], b[n], acc[m][n], 0, 0, 0);
        __builtin_amdgcn_s_setprio(0);
        __builtin_amdgcn_sched_barrier(0);
        __builtin_amdgcn_s_barrier();
        // ---- phase 1: m4-7, stage B(kt+2)
        short8 a2[4];
        #pragma unroll
        for (int m = 0; m < 4; ++m) a2[m] = *(const short8*)&buf[abase + (4 + m) * 512];
        gload_lds16(srcB[0] + koff, sb + dstB[0]);
        gload_lds16(srcB[1] + koff, sb + dstB[1]);
        __builtin_amdgcn_sched_barrier(0);
        __builtin_amdgcn_s_barrier();
        __builtin_amdgcn_s_setprio(1);
        #pragma unroll
        for (int m = 0; m < 4; ++m)
            #pragma unroll
            for (int n = 0; n < 4; ++n)
                acc[4 + m][n] = __builtin_amdgcn_mfma_f32_16x16x32_bf16(a2[m], b[n], acc[4 + m][n], 0, 0, 0);
        __builtin_amdgcn_s_setprio(0);
        __builtin_amdgcn_sched_barrier(0);
        asm volatile("s_waitcnt vmcnt(4)" ::: "memory");   // tile kt+1 landed; kt+2 stays in flight
        __builtin_amdgcn_s_barrier();
    }

    // epilogue: silu(gate)*up -> bf16; frags n0,n1 = gate, n2,n3 = up (same cols)
    #pragma unroll
    for (int m = 0; m < 8; ++m) {
        #pragma unroll
        for (int i = 0; i < 4; ++i) {
            int r = mt * 256 + wm * 128 + m * 16 + l16 * 4 + i;
            if (r >= cnt_e) continue;
            size_t rb = (size_t)(off_e + r) * IDIM;
            #pragma unroll
            for (int nn = 0; nn < 2; ++nn) {
                int col = nt * 128 + wn * 32 + nn * 16 + ln15;
                float gv = acc[m][nn][i], uv = acc[m][2 + nn][i];
                float hv = gv / (1.f + __expf(-gv)) * uv;
                hbuf[rb + col] = f2bf(hv);
            }
        }
    }
}

// ---------------- GEMM2: pb = bf16( tokw * (h @ W2^T) ) ----------------
// 256 rows x 128 cols, BK=32, 4 circular buffers (4x24KB), vmcnt(3).
// 512 thr / 8 waves (2M x 4N). grid (HDIM/128=8, 16, NEXP)

__global__ __launch_bounds__(512, 1) void gemm2_k(
    const unsigned short* __restrict__ hbuf, const unsigned short* __restrict__ w2b,
    const int* __restrict__ offs, const float* __restrict__ tokw,
    unsigned short* __restrict__ pb)
{
    extern __shared__ unsigned short lds[];   // 4 x 12288 ushorts
    const int e = blockIdx.z;
    const int off_e = offs[e];
    const int cnt_e = offs[e + 1] - off_e;
    const int mt = blockIdx.y;
    if (mt * 256 >= cnt_e) return;
    const int nt = blockIdx.x;

    const int tid = threadIdx.x;
    const int w = tid >> 6, lane = tid & 63;
    const int ln15 = lane & 15, l16 = lane >> 4;
    const int wm = w >> 2, wn = w & 3;

    const char* srcA[2]; const char* srcB;
    int dstA[2], dstB;
    #pragma unroll
    for (int j = 0; j < 2; ++j) {
        int S = j * 512 + tid;
        int row = S >> 2, sRaw = S & 3;
        int ko = (sRaw ^ (row & 3)) * 8;
        int tr = mt * 256 + row; if (tr >= cnt_e) tr = cnt_e - 1;
        srcA[j] = (const char*)(hbuf + (size_t)(off_e + tr) * IDIM + ko);
        dstA[j] = S * 8;
    }
    {
        int S = tid;
        int row = S >> 2, sRaw = S & 3;
        int ko = (sRaw ^ (row & 3)) * 8;
        srcB = (const char*)(w2b + (size_t)e * (HDIM * IDIM) + (size_t)(nt * 128 + row) * IDIM + ko);
        dstB = 8192 + S * 8;
    }

    const f32x4 z4 = {0.f, 0.f, 0.f, 0.f};
    f32x4 acc[8][2];
    #pragma unroll
    for (int m = 0; m < 8; ++m)
        #pragma unroll
        for (int n = 0; n < 2; ++n) acc[m][n] = z4;

    const int sl = (l16 ^ (ln15 & 3)) * 8;
    const int abase = (wm * 128 + ln15) * 32 + sl;
    const int bbase = 8192 + (wn * 32 + ln15) * 32 + sl;

    #pragma unroll
    for (int t = 0; t < 2; ++t) {
        unsigned short* sb = lds + t * 12288;
        gload_lds16(srcA[0] + t * 64, sb + dstA[0]);
        gload_lds16(srcA[1] + t * 64, sb + dstA[1]);
        gload_lds16(srcB + t * 64, sb + dstB);
    }
    asm volatile("s_waitcnt vmcnt(3)" ::: "memory");
    __builtin_amdgcn_s_barrier();

    #pragma unroll 4
    for (int kt = 0; kt < 64; ++kt) {
        const unsigned short* buf = lds + (kt & 3) * 12288;
        unsigned short* sb = lds + ((kt + 2) & 3) * 12288;
        const size_t koff = (size_t)((kt + 2 < 64) ? kt + 2 : 63) * 64;

        short8 a[8], b[2];
        #pragma unroll
        for (int m = 0; m < 8; ++m) a[m] = *(const short8*)&buf[abase + m * 512];
        #pragma unroll
        for (int n = 0; n < 2; ++n) b[n] = *(const short8*)&buf[bbase + n * 512];
        gload_lds16(srcA[0] + koff, sb + dstA[0]);
        gload_lds16(srcA[1] + koff, sb + dstA[1]);
        gload_lds16(srcB + koff, sb + dstB);
        __builtin_amdgcn_sched_barrier(0);
        __builtin_amdgcn_s_barrier();
        __builtin_amdgcn_s_setprio(1);
        #pragma unroll
        for (int m = 0; m < 8; ++m)
            #pragma unroll
            for (int n = 0; n < 2; ++n)
                acc[m][n] = __builtin_amdgcn_mfma_f32_16x16x32_bf16(a[m], b[n], acc[m][n], 0, 0, 0);
        __builtin_amdgcn_s_setprio(0);
        __builtin_amdgcn_sched_barrier(0);
        asm volatile("s_waitcnt vmcnt(3)" ::: "memory");   // tile kt+1 landed
        __builtin_amdgcn_s_barrier();
    }

    #pragma unroll
    for (int m = 0; m < 8; ++m) {
        #pragma unroll
        for (int i = 0; i < 4; ++i) {
            int r = mt * 256 + wm * 128 + m * 16 + l16 * 4 + i;
            if (r >= cnt_e) continue;
            float wgt = tokw[off_e + r];
            size_t rb = (size_t)(off_e + r) * HDIM;
            #pragma unroll
            for (int n = 0; n < 2; ++n) {
                int col = nt * 128 + wn * 32 + n * 16 + ln15;
                pb[rb + col] = f2bf(wgt * acc[m][n][i]);
            }
        }
    }
}

// ---------------- combine ----------------

__global__ void combine2_k(const unsigned short* __restrict__ pb, const int* __restrict__ pos,
                           float* __restrict__ out) {
    int idx = blockIdx.x * blockDim.x + threadIdx.x;   // T*H/8 threads
    int t = idx >> 7, c8 = idx & 127;
    int p0 = pos[2 * t], p1 = pos[2 * t + 1];
    short8 a = *(const short8*)(pb + (size_t)p0 * HDIM + c8 * 8);
    short8 b = *(const short8*)(pb + (size_t)p1 * HDIM + c8 * 8);
    float4 o0, o1;
    o0.x = bf2f((unsigned short)a[0]) + bf2f((unsigned short)b[0]);
    o0.y = bf2f((unsigned short)a[1]) + bf2f((unsigned short)b[1]);
    o0.z = bf2f((unsigned short)a[2]) + bf2f((unsigned short)b[2]);
    o0.w = bf2f((unsigned short)a[3]) + bf2f((unsigned short)b[3]);
    o1.x = bf2f((unsigned short)a[4]) + bf2f((unsigned short)b[4]);
    o1.y = bf2f((unsigned short)a[5]) + bf2f((unsigned short)b[5]);
    o1.z = bf2f((unsigned short)a[6]) + bf2f((unsigned short)b[6]);
    o1.w = bf2f((unsigned short)a[7]) + bf2f((unsigned short)b[7]);
    float* op = out + (size_t)t * HDIM + c8 * 8;
    ((float4*)op)[0] = o0;
    ((float4*)op)[1] = o1;
}

// ---------------- launch ----------------

extern "C" void kernel_launch(void* const* d_in, const int* in_sizes, int n_in,
                              void* d_out, int out_size, void* d_ws, size_t ws_size,
                              hipStream_t stream) {
    const float* x      = (const float*)d_in[0];
    const float* logits = (const float*)d_in[1];
    const float* w13    = (const float*)d_in[2];
    const float* w2     = (const float*)d_in[3];
    float* out = (float*)d_out;

    char* ws = (char*)d_ws;
    size_t off = 0;
    auto carve = [&](size_t bytes) -> void* {
        void* p = ws + off;
        off = (off + bytes + 255) & ~(size_t)255;
        return p;
    };
    int*   cnt    = (int*)carve(NEXP * 4);
    int*   offs   = (int*)carve((NEXP + 1) * 4);
    int*   cursor = (int*)carve(NEXP * 4);
    int*   eids   = (int*)carve((size_t)T_TOK * 2 * 4);
    float* ews    = (float*)carve((size_t)T_TOK * 2 * 4);
    int*   tokid  = (int*)carve((size_t)(T_TOK * TOPK + 256) * 4);
    float* tokw   = (float*)carve((size_t)T_TOK * TOPK * 4);
    int*   pos    = (int*)carve((size_t)T_TOK * TOPK * 4);
    unsigned short* xb   = (unsigned short*)carve((size_t)T_TOK * HDIM * 2);
    unsigned short* w13b = (unsigned short*)carve((size_t)NEXP * 2 * IDIM * HDIM * 2);
    unsigned short* w2b  = (unsigned short*)carve((size_t)NEXP * HDIM * IDIM * 2);
    unsigned short* hbuf = (unsigned short*)carve((size_t)T_TOK * TOPK * IDIM * 2);
    unsigned short* pb   = (unsigned short*)carve((size_t)T_TOK * TOPK * HDIM * 2);

    hipFuncSetAttribute(reinterpret_cast<const void*>(gemm1_k),
                        hipFuncAttributeMaxDynamicSharedMemorySize, 131072);
    hipFuncSetAttribute(reinterpret_cast<const void*>(gemm2_k),
                        hipFuncAttributeMaxDynamicSharedMemorySize, 98304);

    init_k<<<1, 64, 0, stream>>>(cnt);
    router_k<<<T_TOK / 256, 256, 0, stream>>>(logits, cnt, eids, ews);
    offs_k<<<1, 1, 0, stream>>>(cnt, offs, cursor);
    scatter_k<<<T_TOK / 256, 256, 0, stream>>>(eids, ews, cursor, tokid, tokw, pos);

    cvt_all_k<<<4096, 256, 0, stream>>>(x, w13, w2, xb, w13b, w2b);

    gemm1_k<<<dim3(IDIM / 128, 16, NEXP), 512, 131072, stream>>>(xb, w13b, tokid, offs, hbuf);
    gemm2_k<<<dim3(HDIM / 128, 16, NEXP), 512, 98304, stream>>>(hbuf, w2b, offs, tokw, pb);

    combine2_k<<<(T_TOK * HDIM / 8) / 256, 256, 0, stream>>>(pb, pos, out);
}

// Round 4
// 297.335 us; speedup vs baseline: 1.0760x; 1.0760x over previous
//
#include <hip/hip_runtime.h>
#include <hip/hip_bf16.h>
#include <stdint.h>

#define T_TOK 4096
#define NEXP  8
#define HDIM  1024
#define IDIM  2048
#define TOPK  2

typedef __attribute__((ext_vector_type(8))) short short8;
typedef __attribute__((ext_vector_type(4))) float f32x4;

__device__ __forceinline__ unsigned short f2bf(float f) {
    union { float f; unsigned int u; } v; v.f = f;
    unsigned int u = v.u;
    return (unsigned short)((u + 0x7fffu + ((u >> 16) & 1u)) >> 16);
}
__device__ __forceinline__ float bf2f(unsigned short s) {
    union { unsigned int u; float f; } v; v.u = ((unsigned int)s) << 16;
    return v.f;
}
__device__ __forceinline__ void gload_lds16(const void* g, void* l) {
    __builtin_amdgcn_global_load_lds(
        (const __attribute__((address_space(1))) unsigned int*)g,
        (__attribute__((address_space(3))) unsigned int*)l,
        16, 0, 0);
}

// ---------------- routing ----------------

__global__ void init_k(int* cnt) {
    if (threadIdx.x < NEXP) cnt[threadIdx.x] = 0;
}

__global__ void router_k(const float* __restrict__ logits, int* __restrict__ cnt,
                         int* __restrict__ eids, float* __restrict__ ews) {
    int t = blockIdx.x * blockDim.x + threadIdx.x;
    if (t >= T_TOK) return;
    const float4* lp = (const float4*)(logits + (size_t)t * NEXP);
    float4 a = lp[0], b = lp[1];
    float l[NEXP] = {a.x, a.y, a.z, a.w, b.x, b.y, b.z, b.w};
    int e0 = 0; float b0 = l[0];
    #pragma unroll
    for (int e = 1; e < NEXP; ++e) if (l[e] > b0) { b0 = l[e]; e0 = e; }
    int e1 = -1; float b1 = -1e30f;
    #pragma unroll
    for (int e = 0; e < NEXP; ++e) { if (e == e0) continue; if (l[e] > b1) { b1 = l[e]; e1 = e; } }
    float tt = __expf(b1 - b0);
    float w0 = 1.0f / (1.0f + tt);
    float w1 = 1.0f - w0;
    eids[2 * t] = e0; eids[2 * t + 1] = e1;
    ews[2 * t] = w0;  ews[2 * t + 1] = w1;
    atomicAdd(&cnt[e0], 1); atomicAdd(&cnt[e1], 1);
}

__global__ void offs_k(const int* __restrict__ cnt, int* __restrict__ offs, int* __restrict__ cursor) {
    if (threadIdx.x == 0) {
        int s = 0;
        for (int e = 0; e < NEXP; ++e) { offs[e] = s; cursor[e] = s; s += cnt[e]; }
        offs[NEXP] = s;
    }
}

__global__ void scatter_k(const int* __restrict__ eids, const float* __restrict__ ews,
                          int* __restrict__ cursor, int* __restrict__ tokid,
                          float* __restrict__ tokw, int* __restrict__ pos) {
    int t = blockIdx.x * blockDim.x + threadIdx.x;
    if (t >= T_TOK) return;
    #pragma unroll
    for (int k = 0; k < TOPK; ++k) {
        int e = eids[2 * t + k];
        int p = atomicAdd(&cursor[e], 1);
        tokid[p] = t; tokw[p] = ews[2 * t + k]; pos[2 * t + k] = p;
    }
}

// ---------------- fp32 -> bf16 convert ----------------

__global__ void cvt_all_k(const float* __restrict__ x, const float* __restrict__ w13,
                          const float* __restrict__ w2, unsigned short* __restrict__ xb,
                          unsigned short* __restrict__ w13b, unsigned short* __restrict__ w2b) {
    const int n0 = T_TOK * HDIM / 8;
    const int n1 = NEXP * 2 * IDIM * HDIM / 8;
    const int n2 = NEXP * HDIM * IDIM / 8;
    const int total = n0 + n1 + n2;
    for (int i = blockIdx.x * blockDim.x + threadIdx.x; i < total; i += gridDim.x * blockDim.x) {
        const float* s; unsigned short* d; int j;
        if (i < n0) { s = x; d = xb; j = i; }
        else if (i < n0 + n1) { s = w13; d = w13b; j = i - n0; }
        else { s = w2; d = w2b; j = i - n0 - n1; }
        const float4* p = (const float4*)(s + (size_t)j * 8);
        float4 a = p[0], b = p[1];
        union { unsigned short us[8]; short8 v; } r;
        r.us[0] = f2bf(a.x); r.us[1] = f2bf(a.y); r.us[2] = f2bf(a.z); r.us[3] = f2bf(a.w);
        r.us[4] = f2bf(b.x); r.us[5] = f2bf(b.y); r.us[6] = f2bf(b.z); r.us[7] = f2bf(b.w);
        *(short8*)(d + (size_t)j * 8) = r.v;
    }
}

// ---------------- GEMM1: h = silu(x@W1^T) * (x@W3^T) ----------------
// BM=128 tokens, 128 out-cols (B = 256 rows: per-wn 32 gate + 32 up), BK=64.
// 3-buffer circular LDS (3 x 48KB), stage tile kt+2 while computing kt,
// counted vmcnt(6). 512 thr / 8 waves (2M x 4N), wave = 64 rows x 64 B-rows.
// grid (IDIM/128=16, 64, NEXP)

#define G1T 24576   // ushorts per tile buffer

__global__ __launch_bounds__(512, 1) void gemm1_k(
    const unsigned short* __restrict__ xb, const unsigned short* __restrict__ w13b,
    const int* __restrict__ tokid, const int* __restrict__ offs,
    unsigned short* __restrict__ hbuf)
{
    extern __shared__ unsigned short lds[];   // 3 x G1T
    const int e = blockIdx.z;
    const int off_e = offs[e];
    const int cnt_e = offs[e + 1] - off_e;
    const int mt = blockIdx.y;
    if (mt * 128 >= cnt_e) return;
    const int nt = blockIdx.x;

    const int tid = threadIdx.x;
    const int w = tid >> 6, lane = tid & 63;
    const int ln15 = lane & 15, l16 = lane >> 4;
    const int wm = w >> 2, wn = w & 3;

    // staging sources (tile 0); A: 128x64 = 2 chunks/thr, B: 256x64 = 4 chunks/thr
    const char* srcA[2]; int dstA[2];
    #pragma unroll
    for (int j = 0; j < 2; ++j) {
        int S = j * 512 + tid;
        int row = S >> 3, slot = S & 7;
        int ko = (slot ^ (row & 7)) * 8;
        int tr = mt * 128 + row; if (tr >= cnt_e) tr = cnt_e - 1;
        srcA[j] = (const char*)(xb + (size_t)tokid[off_e + tr] * HDIM + ko);
        dstA[j] = S * 8;
    }
    const char* srcB[4]; int dstB[4];
    #pragma unroll
    for (int j = 0; j < 4; ++j) {
        int S = j * 512 + tid;
        int row = S >> 3, slot = S & 7;
        int ko = (slot ^ (row & 7)) * 8;
        int grp = row >> 6, sub = row & 63;
        int gr = (sub < 32) ? (nt * 128 + grp * 32 + sub)
                            : (IDIM + nt * 128 + grp * 32 + (sub - 32));
        srcB[j] = (const char*)(w13b + (size_t)e * (2 * IDIM * HDIM) + (size_t)gr * HDIM + ko);
        dstB[j] = 8192 + S * 8;
    }

    const f32x4 z4 = {0.f, 0.f, 0.f, 0.f};
    f32x4 acc[4][4];
    #pragma unroll
    for (int m = 0; m < 4; ++m)
        #pragma unroll
        for (int n = 0; n < 4; ++n) acc[m][n] = z4;

    // fragment read offsets (ushort units)
    const int arow = wm * 64 + ln15;
    const int brow = wn * 64 + ln15;
    const int axor = arow & 7, bxor = brow & 7;
    const int aoff0 = arow * 64 + ((0 + l16) ^ axor) * 8;
    const int aoff1 = arow * 64 + ((4 + l16) ^ axor) * 8;
    const int boff0 = 8192 + brow * 64 + ((0 + l16) ^ bxor) * 8;
    const int boff1 = 8192 + brow * 64 + ((4 + l16) ^ bxor) * 8;

    // prologue: stage tiles 0,1
    #pragma unroll
    for (int t = 0; t < 2; ++t) {
        unsigned short* sb = lds + t * G1T;
        #pragma unroll
        for (int j = 0; j < 2; ++j) gload_lds16(srcA[j] + t * 128, sb + dstA[j]);
        #pragma unroll
        for (int j = 0; j < 4; ++j) gload_lds16(srcB[j] + t * 128, sb + dstB[j]);
    }
    asm volatile("s_waitcnt vmcnt(6)" ::: "memory");
    __builtin_amdgcn_s_barrier();

    int o0 = 0, o1 = G1T, o2 = 2 * G1T;
    const int KT = HDIM / 64;   // 16
    for (int kt = 0; kt < KT; ++kt) {
        const unsigned short* buf = lds + o0;
        unsigned short* sb = lds + o2;
        const int koff = (kt + 2) * 128;
        const bool doStage = (kt + 2 < KT);

        // ---- phase 0: kk=0
        short8 a[4], b[4];
        #pragma unroll
        for (int m = 0; m < 4; ++m) a[m] = *(const short8*)&buf[aoff0 + m * 1024];
        #pragma unroll
        for (int n = 0; n < 4; ++n) b[n] = *(const short8*)&buf[boff0 + n * 1024];
        if (doStage) {
            gload_lds16(srcA[0] + koff, sb + dstA[0]);
            gload_lds16(srcA[1] + koff, sb + dstA[1]);
            gload_lds16(srcB[0] + koff, sb + dstB[0]);
        }
        __builtin_amdgcn_sched_barrier(0);
        __builtin_amdgcn_s_barrier();
        asm volatile("s_waitcnt lgkmcnt(0)" ::: "memory");
        __builtin_amdgcn_sched_barrier(0);
        __builtin_amdgcn_s_setprio(1);
        #pragma unroll
        for (int m = 0; m < 4; ++m)
            #pragma unroll
            for (int n = 0; n < 4; ++n)
                acc[m][n] = __builtin_amdgcn_mfma_f32_16x16x32_bf16(a[m], b[n], acc[m][n], 0, 0, 0);
        __builtin_amdgcn_s_setprio(0);
        __builtin_amdgcn_sched_barrier(0);
        __builtin_amdgcn_s_barrier();

        // ---- phase 1: kk=1
        short8 a2[4], b2[4];
        #pragma unroll
        for (int m = 0; m < 4; ++m) a2[m] = *(const short8*)&buf[aoff1 + m * 1024];
        #pragma unroll
        for (int n = 0; n < 4; ++n) b2[n] = *(const short8*)&buf[boff1 + n * 1024];
        if (doStage) {
            gload_lds16(srcB[1] + koff, sb + dstB[1]);
            gload_lds16(srcB[2] + koff, sb + dstB[2]);
            gload_lds16(srcB[3] + koff, sb + dstB[3]);
        }
        __builtin_amdgcn_sched_barrier(0);
        __builtin_amdgcn_s_barrier();
        asm volatile("s_waitcnt lgkmcnt(0)" ::: "memory");
        __builtin_amdgcn_sched_barrier(0);
        __builtin_amdgcn_s_setprio(1);
        #pragma unroll
        for (int m = 0; m < 4; ++m)
            #pragma unroll
            for (int n = 0; n < 4; ++n)
                acc[m][n] = __builtin_amdgcn_mfma_f32_16x16x32_bf16(a2[m], b2[n], acc[m][n], 0, 0, 0);
        __builtin_amdgcn_s_setprio(0);
        __builtin_amdgcn_sched_barrier(0);

        // end of K-tile: counted wait (tile kt+1 landed; kt+2 stays in flight)
        if (kt < KT - 2) {
            asm volatile("s_waitcnt vmcnt(6)" ::: "memory");
            __builtin_amdgcn_s_barrier();
        } else if (kt == KT - 2) {
            asm volatile("s_waitcnt vmcnt(0)" ::: "memory");
            __builtin_amdgcn_s_barrier();
        }
        int tmp = o0; o0 = o1; o1 = o2; o2 = tmp;
    }

    // epilogue: silu(gate)*up -> bf16; n0,n1 = gate, n2,n3 = up (same cols)
    #pragma unroll
    for (int m = 0; m < 4; ++m) {
        #pragma unroll
        for (int i = 0; i < 4; ++i) {
            int r = mt * 128 + wm * 64 + m * 16 + l16 * 4 + i;
            if (r >= cnt_e) continue;
            size_t rb = (size_t)(off_e + r) * IDIM;
            #pragma unroll
            for (int nn = 0; nn < 2; ++nn) {
                int col = nt * 128 + wn * 32 + nn * 16 + ln15;
                float gv = acc[m][nn][i], uv = acc[m][2 + nn][i];
                float hv = gv / (1.f + __expf(-gv)) * uv;
                hbuf[rb + col] = f2bf(hv);
            }
        }
    }
}

// ---------------- GEMM2: pb = bf16( tokw * (h @ W2^T) ) ----------------
// BM=256 rows, BN=128 cols, BK=64, 3-buffer circular (3 x 48KB), vmcnt(6).
// 512 thr / 8 waves (4M x 2N), wave = 64 rows x 64 cols.
// grid (HDIM/128=8, 32, NEXP)

#define G2T 24576

__global__ __launch_bounds__(512, 1) void gemm2_k(
    const unsigned short* __restrict__ hbuf, const unsigned short* __restrict__ w2b,
    const int* __restrict__ offs, const float* __restrict__ tokw,
    unsigned short* __restrict__ pb)
{
    extern __shared__ unsigned short lds[];   // 3 x G2T
    const int e = blockIdx.z;
    const int off_e = offs[e];
    const int cnt_e = offs[e + 1] - off_e;
    const int mt = blockIdx.y;
    if (mt * 256 >= cnt_e) return;
    const int nt = blockIdx.x;

    const int tid = threadIdx.x;
    const int w = tid >> 6, lane = tid & 63;
    const int ln15 = lane & 15, l16 = lane >> 4;
    const int wm = w >> 1, wn = w & 1;

    // A: 256x64 = 4 chunks/thr; B: 128x64 = 2 chunks/thr
    const char* srcA[4]; int dstA[4];
    #pragma unroll
    for (int j = 0; j < 4; ++j) {
        int S = j * 512 + tid;
        int row = S >> 3, slot = S & 7;
        int ko = (slot ^ (row & 7)) * 8;
        int tr = mt * 256 + row; if (tr >= cnt_e) tr = cnt_e - 1;
        srcA[j] = (const char*)(hbuf + (size_t)(off_e + tr) * IDIM + ko);
        dstA[j] = S * 8;
    }
    const char* srcB[2]; int dstB[2];
    #pragma unroll
    for (int j = 0; j < 2; ++j) {
        int S = j * 512 + tid;
        int row = S >> 3, slot = S & 7;
        int ko = (slot ^ (row & 7)) * 8;
        srcB[j] = (const char*)(w2b + (size_t)e * (HDIM * IDIM) + (size_t)(nt * 128 + row) * IDIM + ko);
        dstB[j] = 16384 + S * 8;
    }

    const f32x4 z4 = {0.f, 0.f, 0.f, 0.f};
    f32x4 acc[4][4];
    #pragma unroll
    for (int m = 0; m < 4; ++m)
        #pragma unroll
        for (int n = 0; n < 4; ++n) acc[m][n] = z4;

    const int arow = wm * 64 + ln15;
    const int brow = wn * 64 + ln15;
    const int axor = arow & 7, bxor = brow & 7;
    const int aoff0 = arow * 64 + ((0 + l16) ^ axor) * 8;
    const int aoff1 = arow * 64 + ((4 + l16) ^ axor) * 8;
    const int boff0 = 16384 + brow * 64 + ((0 + l16) ^ bxor) * 8;
    const int boff1 = 16384 + brow * 64 + ((4 + l16) ^ bxor) * 8;

    #pragma unroll
    for (int t = 0; t < 2; ++t) {
        unsigned short* sb = lds + t * G2T;
        #pragma unroll
        for (int j = 0; j < 4; ++j) gload_lds16(srcA[j] + t * 128, sb + dstA[j]);
        #pragma unroll
        for (int j = 0; j < 2; ++j) gload_lds16(srcB[j] + t * 128, sb + dstB[j]);
    }
    asm volatile("s_waitcnt vmcnt(6)" ::: "memory");
    __builtin_amdgcn_s_barrier();

    int o0 = 0, o1 = G2T, o2 = 2 * G2T;
    const int KT = IDIM / 64;   // 32
    for (int kt = 0; kt < KT; ++kt) {
        const unsigned short* buf = lds + o0;
        unsigned short* sb = lds + o2;
        const int koff = (kt + 2) * 128;
        const bool doStage = (kt + 2 < KT);

        // ---- phase 0: kk=0
        short8 a[4], b[4];
        #pragma unroll
        for (int m = 0; m < 4; ++m) a[m] = *(const short8*)&buf[aoff0 + m * 1024];
        #pragma unroll
        for (int n = 0; n < 4; ++n) b[n] = *(const short8*)&buf[boff0 + n * 1024];
        if (doStage) {
            gload_lds16(srcA[0] + koff, sb + dstA[0]);
            gload_lds16(srcA[1] + koff, sb + dstA[1]);
            gload_lds16(srcB[0] + koff, sb + dstB[0]);
        }
        __builtin_amdgcn_sched_barrier(0);
        __builtin_amdgcn_s_barrier();
        asm volatile("s_waitcnt lgkmcnt(0)" ::: "memory");
        __builtin_amdgcn_sched_barrier(0);
        __builtin_amdgcn_s_setprio(1);
        #pragma unroll
        for (int m = 0; m < 4; ++m)
            #pragma unroll
            for (int n = 0; n < 4; ++n)
                acc[m][n] = __builtin_amdgcn_mfma_f32_16x16x32_bf16(a[m], b[n], acc[m][n], 0, 0, 0);
        __builtin_amdgcn_s_setprio(0);
        __builtin_amdgcn_sched_barrier(0);
        __builtin_amdgcn_s_barrier();

        // ---- phase 1: kk=1
        short8 a2[4], b2[4];
        #pragma unroll
        for (int m = 0; m < 4; ++m) a2[m] = *(const short8*)&buf[aoff1 + m * 1024];
        #pragma unroll
        for (int n = 0; n < 4; ++n) b2[n] = *(const short8*)&buf[boff1 + n * 1024];
        if (doStage) {
            gload_lds16(srcA[2] + koff, sb + dstA[2]);
            gload_lds16(srcA[3] + koff, sb + dstA[3]);
            gload_lds16(srcB[1] + koff, sb + dstB[1]);
        }
        __builtin_amdgcn_sched_barrier(0);
        __builtin_amdgcn_s_barrier();
        asm volatile("s_waitcnt lgkmcnt(0)" ::: "memory");
        __builtin_amdgcn_sched_barrier(0);
        __builtin_amdgcn_s_setprio(1);
        #pragma unroll
        for (int m = 0; m < 4; ++m)
            #pragma unroll
            for (int n = 0; n < 4; ++n)
                acc[m][n] = __builtin_amdgcn_mfma_f32_16x16x32_bf16(a2[m], b2[n], acc[m][n], 0, 0, 0);
        __builtin_amdgcn_s_setprio(0);
        __builtin_amdgcn_sched_barrier(0);

        if (kt < KT - 2) {
            asm volatile("s_waitcnt vmcnt(6)" ::: "memory");
            __builtin_amdgcn_s_barrier();
        } else if (kt == KT - 2) {
            asm volatile("s_waitcnt vmcnt(0)" ::: "memory");
            __builtin_amdgcn_s_barrier();
        }
        int tmp = o0; o0 = o1; o1 = o2; o2 = tmp;
    }

    #pragma unroll
    for (int m = 0; m < 4; ++m) {
        #pragma unroll
        for (int i = 0; i < 4; ++i) {
            int r = mt * 256 + wm * 64 + m * 16 + l16 * 4 + i;
            if (r >= cnt_e) continue;
            float wgt = tokw[off_e + r];
            size_t rb = (size_t)(off_e + r) * HDIM;
            #pragma unroll
            for (int n = 0; n < 4; ++n) {
                int col = nt * 128 + wn * 64 + n * 16 + ln15;
                pb[rb + col] = f2bf(wgt * acc[m][n][i]);
            }
        }
    }
}

// ---------------- combine ----------------

__global__ void combine2_k(const unsigned short* __restrict__ pb, const int* __restrict__ pos,
                           float* __restrict__ out) {
    int idx = blockIdx.x * blockDim.x + threadIdx.x;   // T*H/8 threads
    int t = idx >> 7, c8 = idx & 127;
    int p0 = pos[2 * t], p1 = pos[2 * t + 1];
    short8 a = *(const short8*)(pb + (size_t)p0 * HDIM + c8 * 8);
    short8 b = *(const short8*)(pb + (size_t)p1 * HDIM + c8 * 8);
    float4 o0, o1;
    o0.x = bf2f((unsigned short)a[0]) + bf2f((unsigned short)b[0]);
    o0.y = bf2f((unsigned short)a[1]) + bf2f((unsigned short)b[1]);
    o0.z = bf2f((unsigned short)a[2]) + bf2f((unsigned short)b[2]);
    o0.w = bf2f((unsigned short)a[3]) + bf2f((unsigned short)b[3]);
    o1.x = bf2f((unsigned short)a[4]) + bf2f((unsigned short)b[4]);
    o1.y = bf2f((unsigned short)a[5]) + bf2f((unsigned short)b[5]);
    o1.z = bf2f((unsigned short)a[6]) + bf2f((unsigned short)b[6]);
    o1.w = bf2f((unsigned short)a[7]) + bf2f((unsigned short)b[7]);
    float* op = out + (size_t)t * HDIM + c8 * 8;
    ((float4*)op)[0] = o0;
    ((float4*)op)[1] = o1;
}

// ---------------- launch ----------------

extern "C" void kernel_launch(void* const* d_in, const int* in_sizes, int n_in,
                              void* d_out, int out_size, void* d_ws, size_t ws_size,
                              hipStream_t stream) {
    const float* x      = (const float*)d_in[0];
    const float* logits = (const float*)d_in[1];
    const float* w13    = (const float*)d_in[2];
    const float* w2     = (const float*)d_in[3];
    float* out = (float*)d_out;

    char* ws = (char*)d_ws;
    size_t off = 0;
    auto carve = [&](size_t bytes) -> void* {
        void* p = ws + off;
        off = (off + bytes + 255) & ~(size_t)255;
        return p;
    };
    int*   cnt    = (int*)carve(NEXP * 4);
    int*   offs   = (int*)carve((NEXP + 1) * 4);
    int*   cursor = (int*)carve(NEXP * 4);
    int*   eids   = (int*)carve((size_t)T_TOK * 2 * 4);
    float* ews    = (float*)carve((size_t)T_TOK * 2 * 4);
    int*   tokid  = (int*)carve((size_t)(T_TOK * TOPK + 256) * 4);
    float* tokw   = (float*)carve((size_t)T_TOK * TOPK * 4);
    int*   pos    = (int*)carve((size_t)T_TOK * TOPK * 4);
    unsigned short* xb   = (unsigned short*)carve((size_t)T_TOK * HDIM * 2);
    unsigned short* w13b = (unsigned short*)carve((size_t)NEXP * 2 * IDIM * HDIM * 2);
    unsigned short* w2b  = (unsigned short*)carve((size_t)NEXP * HDIM * IDIM * 2);
    unsigned short* hbuf = (unsigned short*)carve((size_t)T_TOK * TOPK * IDIM * 2);
    unsigned short* pb   = (unsigned short*)carve((size_t)T_TOK * TOPK * HDIM * 2);

    hipFuncSetAttribute(reinterpret_cast<const void*>(gemm1_k),
                        hipFuncAttributeMaxDynamicSharedMemorySize, 3 * G1T * 2);
    hipFuncSetAttribute(reinterpret_cast<const void*>(gemm2_k),
                        hipFuncAttributeMaxDynamicSharedMemorySize, 3 * G2T * 2);

    init_k<<<1, 64, 0, stream>>>(cnt);
    router_k<<<T_TOK / 256, 256, 0, stream>>>(logits, cnt, eids, ews);
    offs_k<<<1, 1, 0, stream>>>(cnt, offs, cursor);
    scatter_k<<<T_TOK / 256, 256, 0, stream>>>(eids, ews, cursor, tokid, tokw, pos);

    cvt_all_k<<<4096, 256, 0, stream>>>(x, w13, w2, xb, w13b, w2b);

    gemm1_k<<<dim3(IDIM / 128, 64, NEXP), 512, 3 * G1T * 2, stream>>>(xb, w13b, tokid, offs, hbuf);
    gemm2_k<<<dim3(HDIM / 128, 32, NEXP), 512, 3 * G2T * 2, stream>>>(hbuf, w2b, offs, tokw, pb);

    combine2_k<<<(T_TOK * HDIM / 8) / 256, 256, 0, stream>>>(pb, pos, out);
}